// Round 1
// baseline (573.968 us; speedup 1.0000x reference)
//
#include <hip/hip_runtime.h>
#include <hip/hip_bf16.h>

typedef __attribute__((ext_vector_type(8))) short short8;
typedef __attribute__((ext_vector_type(4))) float f32x4;
typedef __attribute__((ext_vector_type(4))) unsigned short u16x4;

#define D 256
#define BM 64

static __device__ __forceinline__ unsigned short f2bf(float f) {
    union { float f; unsigned u; } v; v.f = f;
    return (unsigned short)((v.u + 0x7fffu + ((v.u >> 16) & 1u)) >> 16);
}
static __device__ __forceinline__ float bf2f(unsigned short h) {
    union { unsigned u; float f; } v; v.u = ((unsigned)h) << 16;
    return v.f;
}

// Pack W [K x 256] row-major f32 -> bf16 fragment-ready layout:
// dst[(((ntile*NKK)+kk)*64 + lane)*8 + j] = bf16(W[kk*32 + (lane>>4)*8 + j][ntile*16 + (lane&15)])
__global__ void pack_w_kernel(const float* __restrict__ W, unsigned short* __restrict__ dst,
                              int log2nkk, int total) {
    int p = blockIdx.x * blockDim.x + threadIdx.x;
    if (p >= total) return;
    int j     = p & 7;
    int lane  = (p >> 3) & 63;
    int kk    = (p >> 9) & ((1 << log2nkk) - 1);
    int ntile = p >> (9 + log2nkk);
    int k = kk * 32 + ((lane >> 4) * 8) + j;
    int n = ntile * 16 + (lane & 15);
    dst[p] = f2bf(W[k * D + n]);
}

__global__ void copy_kernel(const float4* __restrict__ src, float4* __restrict__ dst, int n4) {
    int i = blockIdx.x * blockDim.x + threadIdx.x;
    int stride = gridDim.x * blockDim.x;
    for (; i < n4; i += stride) dst[i] = src[i];
}

// Fused gather -> proj GEMM (relu) -> gate GEMM (sigmoid) -> mix -> scatter.
// 64 mapping rows per block, 4 waves, each wave owns a 64x64 column slice.
__global__ __launch_bounds__(256, 2) void fused_kernel(
    const float* __restrict__ prev, const float* __restrict__ cfg,
    const int* __restrict__ kidx, const int* __restrict__ vidx,
    const unsigned short* __restrict__ WuP, const unsigned short* __restrict__ WgP,
    const float* __restrict__ bu, const float* __restrict__ bg,
    float* __restrict__ out)
{
    __shared__ unsigned short Ast[BM * D];  // state, bf16, swizzled rows (512B/row)
    __shared__ unsigned short Aub[BM * D];  // upd, then reused for proj
    char* astB = (char*)Ast;
    char* aubB = (char*)Aub;

    const int t    = threadIdx.x;
    const int lane = t & 63;
    const int wid  = t >> 6;      // 0..3
    const int lr   = lane & 15;   // row-in-A-frag / col-in-B/C-frag
    const int lk   = lane >> 4;   // 0..3 k-subgroup / C row group
    const int base = blockIdx.x * BM;

    // ---- stage: gather 64 state rows + 64 upd rows, f32 -> bf16, swizzled LDS ----
    #pragma unroll
    for (int i = 0; i < 16; ++i) {
        int row = wid * 16 + i;                 // uniform per wave -> scalar loads
        int kr = kidx[base + row];
        int vr = vidx[base + row];
        float4 s = *(const float4*)(prev + (size_t)kr * D + lane * 4);
        float4 u = *(const float4*)(cfg  + (size_t)vr * D + lane * 4);
        int boff = (lane * 8) ^ ((row & 7) << 4);
        u16x4 hs, hu;
        hs.x = f2bf(s.x); hs.y = f2bf(s.y); hs.z = f2bf(s.z); hs.w = f2bf(s.w);
        hu.x = f2bf(u.x); hu.y = f2bf(u.y); hu.z = f2bf(u.z); hu.w = f2bf(u.w);
        *(u16x4*)(astB + row * 512 + boff) = hs;
        *(u16x4*)(aubB + row * 512 + boff) = hu;
    }
    __syncthreads();

    // ---- GEMM1: proj = relu(upd @ Wu + bu), tile 64 x 64 per wave, K = 256 ----
    f32x4 acc[4][4];
    #pragma unroll
    for (int fm = 0; fm < 4; ++fm)
        #pragma unroll
        for (int fn = 0; fn < 4; ++fn)
            acc[fm][fn] = (f32x4){0.f, 0.f, 0.f, 0.f};

    #pragma unroll
    for (int kk = 0; kk < 8; ++kk) {
        short8 a[4], b[4];
        #pragma unroll
        for (int fm = 0; fm < 4; ++fm) {
            int row = fm * 16 + lr;
            int boff = (kk * 64 + lk * 16) ^ ((row & 7) << 4);
            a[fm] = *(const short8*)(aubB + row * 512 + boff);
        }
        #pragma unroll
        for (int fn = 0; fn < 4; ++fn) {
            int ntile = wid * 4 + fn;
            b[fn] = *(const short8*)(WuP + ((size_t)(ntile * 8 + kk) * 64 + lane) * 8);
        }
        #pragma unroll
        for (int fm = 0; fm < 4; ++fm)
            #pragma unroll
            for (int fn = 0; fn < 4; ++fn)
                acc[fm][fn] = __builtin_amdgcn_mfma_f32_16x16x32_bf16(a[fm], b[fn], acc[fm][fn], 0, 0, 0);
    }

    float bu4[4];
    #pragma unroll
    for (int fn = 0; fn < 4; ++fn) bu4[fn] = bu[wid * 64 + fn * 16 + lr];

    __syncthreads();   // all waves done reading Aub before proj overwrite

    // relu + bias; keep f32 proj in acc; write bf16 proj into Aub (swizzled)
    #pragma unroll
    for (int fm = 0; fm < 4; ++fm) {
        #pragma unroll
        for (int fn = 0; fn < 4; ++fn) {
            #pragma unroll
            for (int i = 0; i < 4; ++i) {
                float p = acc[fm][fn][i] + bu4[fn];
                p = p > 0.f ? p : 0.f;
                acc[fm][fn][i] = p;
                int row = fm * 16 + lk * 4 + i;
                int col = wid * 64 + fn * 16 + lr;
                int boff = (col * 2) ^ ((row & 7) << 4);
                *(unsigned short*)(aubB + row * 512 + boff) = f2bf(p);
            }
        }
    }
    __syncthreads();

    // ---- GEMM2: logits = [state, proj] @ Wg + bg, K = 512 ----
    f32x4 acc2[4][4];
    #pragma unroll
    for (int fm = 0; fm < 4; ++fm)
        #pragma unroll
        for (int fn = 0; fn < 4; ++fn)
            acc2[fm][fn] = (f32x4){0.f, 0.f, 0.f, 0.f};

    #pragma unroll
    for (int kk = 0; kk < 16; ++kk) {
        const char* Asrc = (kk < 8) ? astB : aubB;   // rows 0-255 of Wg hit state, 256-511 hit proj
        int kkl = kk & 7;
        short8 a[4], b[4];
        #pragma unroll
        for (int fm = 0; fm < 4; ++fm) {
            int row = fm * 16 + lr;
            int boff = (kkl * 64 + lk * 16) ^ ((row & 7) << 4);
            a[fm] = *(const short8*)(Asrc + row * 512 + boff);
        }
        #pragma unroll
        for (int fn = 0; fn < 4; ++fn) {
            int ntile = wid * 4 + fn;
            b[fn] = *(const short8*)(WgP + ((size_t)(ntile * 16 + kk) * 64 + lane) * 8);
        }
        #pragma unroll
        for (int fm = 0; fm < 4; ++fm)
            #pragma unroll
            for (int fn = 0; fn < 4; ++fn)
                acc2[fm][fn] = __builtin_amdgcn_mfma_f32_16x16x32_bf16(a[fm], b[fn], acc2[fm][fn], 0, 0, 0);
    }

    // ---- epilogue: gate = sigmoid(logits + bg); out = g*state + (1-g)*proj ----
    float bg4[4];
    #pragma unroll
    for (int fn = 0; fn < 4; ++fn) bg4[fn] = bg[wid * 64 + fn * 16 + lr];

    #pragma unroll
    for (int fm = 0; fm < 4; ++fm) {
        #pragma unroll
        for (int i = 0; i < 4; ++i) {
            int row = fm * 16 + lk * 4 + i;
            int kr = kidx[base + row];
            float* orow = out + (size_t)kr * D;
            #pragma unroll
            for (int fn = 0; fn < 4; ++fn) {
                int col = wid * 64 + fn * 16 + lr;
                float x = acc2[fm][fn][i] + bg4[fn];
                float g = 1.f / (1.f + __expf(-x));
                float st = bf2f(*(const unsigned short*)(astB + row * 512 + ((col * 2) ^ ((row & 7) << 4))));
                orow[col] = g * st + (1.f - g) * acc[fm][fn][i];
            }
        }
    }
}

extern "C" void kernel_launch(void* const* d_in, const int* in_sizes, int n_in,
                              void* d_out, int out_size, void* d_ws, size_t ws_size,
                              hipStream_t stream) {
    const float* prev = (const float*)d_in[0];
    const float* cfg  = (const float*)d_in[1];
    const int* kidx   = (const int*)d_in[2];
    const int* vidx   = (const int*)d_in[3];
    const float* Wu   = (const float*)d_in[4];
    const float* bu   = (const float*)d_in[5];
    const float* Wg   = (const float*)d_in[6];
    const float* bg   = (const float*)d_in[7];
    float* out = (float*)d_out;

    unsigned short* WuP = (unsigned short*)d_ws;          // 256*256 bf16 = 128KB
    unsigned short* WgP = WuP + 256 * 256;                // 512*256 bf16 = 256KB

    const int M = in_sizes[2];          // 400000
    const int totalWu = 256 * 256;
    const int totalWg = 512 * 256;
    const int n4 = in_sizes[0] / 4;     // 32M float4

    pack_w_kernel<<<(totalWu + 255) / 256, 256, 0, stream>>>(Wu, WuP, 3, totalWu);
    pack_w_kernel<<<(totalWg + 255) / 256, 256, 0, stream>>>(Wg, WgP, 4, totalWg);
    copy_kernel<<<4096, 256, 0, stream>>>((const float4*)prev, (float4*)out, n4);
    fused_kernel<<<M / BM, 256, 0, stream>>>(prev, cfg, kidx, vidx, WuP, WgP, bu, bg, out);
}

// Round 3
// 522.842 us; speedup vs baseline: 1.0978x; 1.0978x over previous
//
#include <hip/hip_runtime.h>
#include <hip/hip_bf16.h>

typedef __attribute__((ext_vector_type(8))) short short8;
typedef __attribute__((ext_vector_type(4))) float f32x4;
typedef __attribute__((ext_vector_type(4))) unsigned short u16x4;

#define D 256
#define BM 32

static __device__ __forceinline__ unsigned short f2bf(float f) {
    union { __hip_bfloat16 h; unsigned short u; } v;
    v.h = __float2bfloat16(f);
    return v.u;
}
static __device__ __forceinline__ float bf2f(unsigned short h) {
    union { unsigned u; float f; } v; v.u = ((unsigned)h) << 16;
    return v.f;
}

// Pack W [K x 256] row-major f32 -> bf16 fragment-ready layout:
// dst[(((ntile*NKK)+kk)*64 + lane)*8 + j] = bf16(W[kk*32 + (lane>>4)*8 + j][ntile*16 + (lane&15)])
__global__ void pack_w_kernel(const float* __restrict__ W, unsigned short* __restrict__ dst,
                              int log2nkk, int total) {
    int p = blockIdx.x * blockDim.x + threadIdx.x;
    if (p >= total) return;
    int j     = p & 7;
    int lane  = (p >> 3) & 63;
    int kk    = (p >> 9) & ((1 << log2nkk) - 1);
    int ntile = p >> (9 + log2nkk);
    int k = kk * 32 + ((lane >> 4) * 8) + j;
    int n = ntile * 16 + (lane & 15);
    dst[p] = f2bf(W[k * D + n]);
}

__global__ void clear_flags_kernel(unsigned* __restrict__ f, int n) {
    int i = blockIdx.x * blockDim.x + threadIdx.x;
    if (i < n) f[i] = 0u;
}

__global__ void scatter_flags_kernel(const int* __restrict__ kidx,
                                     unsigned char* __restrict__ flags, int m) {
    int i = blockIdx.x * blockDim.x + threadIdx.x;
    if (i < m) flags[kidx[i]] = 1;
}

// One wave per AST row; copy only rows NOT covered by the scatter.
__global__ void copy_rows_kernel(const f32x4* __restrict__ src, f32x4* __restrict__ dst,
                                 const unsigned char* __restrict__ flags, int nrows) {
    int w    = (blockIdx.x * blockDim.x + threadIdx.x) >> 6;
    int lane = threadIdx.x & 63;
    int nw   = (gridDim.x * blockDim.x) >> 6;
    for (int row = w; row < nrows; row += nw) {
        if (flags[row]) continue;
        size_t idx = (size_t)row * 64 + lane;
        f32x4 v = __builtin_nontemporal_load(src + idx);
        __builtin_nontemporal_store(v, dst + idx);
    }
}

// Fused gather -> proj GEMM (relu) -> gate GEMM (sigmoid) -> mix -> scatter.
// 32 mapping rows per block, 4 waves, each wave owns a 32x64 column slice.
__global__ __launch_bounds__(256, 5) void fused_kernel(
    const float* __restrict__ prev, const float* __restrict__ cfg,
    const int* __restrict__ kidx, const int* __restrict__ vidx,
    const unsigned short* __restrict__ WuP, const unsigned short* __restrict__ WgP,
    const float* __restrict__ bu, const float* __restrict__ bg,
    float* __restrict__ out)
{
    __shared__ unsigned short Ast[BM * D];  // state, bf16, swizzled rows (512B/row)
    __shared__ unsigned short Aub[BM * D];  // upd, then reused for proj
    char* astB = (char*)Ast;
    char* aubB = (char*)Aub;

    const int t    = threadIdx.x;
    const int lane = t & 63;
    const int wid  = t >> 6;      // 0..3
    const int lr   = lane & 15;   // row-in-A-frag / col-in-B/C-frag
    const int lk   = lane >> 4;   // 0..3 k-subgroup / C row group
    const int base = blockIdx.x * BM;

    // ---- stage: gather 32 state rows + 32 upd rows, f32 -> bf16, swizzled LDS ----
    #pragma unroll
    for (int i = 0; i < 8; ++i) {
        int row = wid * 8 + i;                 // uniform per wave
        int kr = kidx[base + row];
        int vr = vidx[base + row];
        f32x4 s = *(const f32x4*)(prev + (size_t)kr * D + lane * 4);
        f32x4 u = *(const f32x4*)(cfg  + (size_t)vr * D + lane * 4);
        int boff = (lane * 8) ^ ((row & 7) << 4);
        u16x4 hs, hu;
        hs.x = f2bf(s.x); hs.y = f2bf(s.y); hs.z = f2bf(s.z); hs.w = f2bf(s.w);
        hu.x = f2bf(u.x); hu.y = f2bf(u.y); hu.z = f2bf(u.z); hu.w = f2bf(u.w);
        *(u16x4*)(astB + row * 512 + boff) = hs;
        *(u16x4*)(aubB + row * 512 + boff) = hu;
    }
    __syncthreads();

    // ---- GEMM1: proj = relu(upd @ Wu + bu), tile 32 x 64 per wave, K = 256 ----
    f32x4 acc[2][4];
    #pragma unroll
    for (int fm = 0; fm < 2; ++fm)
        #pragma unroll
        for (int fn = 0; fn < 4; ++fn)
            acc[fm][fn] = (f32x4){0.f, 0.f, 0.f, 0.f};

    #pragma unroll
    for (int kk = 0; kk < 8; ++kk) {
        short8 a[2], b[4];
        #pragma unroll
        for (int fm = 0; fm < 2; ++fm) {
            int row = fm * 16 + lr;
            int boff = (kk * 64 + lk * 16) ^ ((row & 7) << 4);
            a[fm] = *(const short8*)(aubB + row * 512 + boff);
        }
        #pragma unroll
        for (int fn = 0; fn < 4; ++fn) {
            int ntile = wid * 4 + fn;
            b[fn] = *(const short8*)(WuP + ((size_t)(ntile * 8 + kk) * 64 + lane) * 8);
        }
        #pragma unroll
        for (int fm = 0; fm < 2; ++fm)
            #pragma unroll
            for (int fn = 0; fn < 4; ++fn)
                acc[fm][fn] = __builtin_amdgcn_mfma_f32_16x16x32_bf16(a[fm], b[fn], acc[fm][fn], 0, 0, 0);
    }

    float bu4[4];
    #pragma unroll
    for (int fn = 0; fn < 4; ++fn) bu4[fn] = bu[wid * 64 + fn * 16 + lr];

    __syncthreads();   // all waves done reading Aub before proj overwrite

    // relu + bias; write bf16 proj into Aub (swizzled); proj re-read from LDS later
    #pragma unroll
    for (int fm = 0; fm < 2; ++fm) {
        #pragma unroll
        for (int fn = 0; fn < 4; ++fn) {
            #pragma unroll
            for (int i = 0; i < 4; ++i) {
                float p = acc[fm][fn][i] + bu4[fn];
                p = p > 0.f ? p : 0.f;
                int row = fm * 16 + lk * 4 + i;
                int col = wid * 64 + fn * 16 + lr;
                int boff = (col * 2) ^ ((row & 7) << 4);
                *(unsigned short*)(aubB + row * 512 + boff) = f2bf(p);
            }
        }
    }
    __syncthreads();

    // ---- GEMM2: logits = [state, proj] @ Wg + bg, K = 512 ----
    f32x4 acc2[2][4];
    #pragma unroll
    for (int fm = 0; fm < 2; ++fm)
        #pragma unroll
        for (int fn = 0; fn < 4; ++fn)
            acc2[fm][fn] = (f32x4){0.f, 0.f, 0.f, 0.f};

    #pragma unroll
    for (int kk = 0; kk < 16; ++kk) {
        const char* Asrc = (kk < 8) ? astB : aubB;   // rows 0-255 of Wg hit state, 256-511 hit proj
        int kkl = kk & 7;
        short8 a[2], b[4];
        #pragma unroll
        for (int fm = 0; fm < 2; ++fm) {
            int row = fm * 16 + lr;
            int boff = (kkl * 64 + lk * 16) ^ ((row & 7) << 4);
            a[fm] = *(const short8*)(Asrc + row * 512 + boff);
        }
        #pragma unroll
        for (int fn = 0; fn < 4; ++fn) {
            int ntile = wid * 4 + fn;
            b[fn] = *(const short8*)(WgP + ((size_t)(ntile * 16 + kk) * 64 + lane) * 8);
        }
        #pragma unroll
        for (int fm = 0; fm < 2; ++fm)
            #pragma unroll
            for (int fn = 0; fn < 4; ++fn)
                acc2[fm][fn] = __builtin_amdgcn_mfma_f32_16x16x32_bf16(a[fm], b[fn], acc2[fm][fn], 0, 0, 0);
    }

    // ---- epilogue: gate = sigmoid(logits + bg); out = g*state + (1-g)*proj ----
    float bg4[4];
    #pragma unroll
    for (int fn = 0; fn < 4; ++fn) bg4[fn] = bg[wid * 64 + fn * 16 + lr];

    #pragma unroll
    for (int fm = 0; fm < 2; ++fm) {
        #pragma unroll
        for (int i = 0; i < 4; ++i) {
            int row = fm * 16 + lk * 4 + i;
            int kr = kidx[base + row];
            float* orow = out + (size_t)kr * D;
            #pragma unroll
            for (int fn = 0; fn < 4; ++fn) {
                int col = wid * 64 + fn * 16 + lr;
                float x = acc2[fm][fn][i] + bg4[fn];
                float g = 1.f / (1.f + __expf(-x));
                int boff = (col * 2) ^ ((row & 7) << 4);
                float st = bf2f(*(const unsigned short*)(astB + row * 512 + boff));
                float pj = bf2f(*(const unsigned short*)(aubB + row * 512 + boff));
                orow[col] = g * st + (1.f - g) * pj;
            }
        }
    }
}

extern "C" void kernel_launch(void* const* d_in, const int* in_sizes, int n_in,
                              void* d_out, int out_size, void* d_ws, size_t ws_size,
                              hipStream_t stream) {
    const float* prev = (const float*)d_in[0];
    const float* cfg  = (const float*)d_in[1];
    const int* kidx   = (const int*)d_in[2];
    const int* vidx   = (const int*)d_in[3];
    const float* Wu   = (const float*)d_in[4];
    const float* bu   = (const float*)d_in[5];
    const float* Wg   = (const float*)d_in[6];
    const float* bg   = (const float*)d_in[7];
    float* out = (float*)d_out;

    const int N_AST = in_sizes[0] / D;  // 500000
    const int M     = in_sizes[2];      // 400000

    unsigned short* WuP = (unsigned short*)d_ws;          // 256*256 bf16 = 128KB
    unsigned short* WgP = WuP + 256 * 256;                // 512*256 bf16 = 256KB
    unsigned char* flags = (unsigned char*)(WgP + 512 * 256);  // N_AST bytes

    const int totalWu = 256 * 256;
    const int totalWg = 512 * 256;
    const int nflag4  = (N_AST + 3) / 4;

    pack_w_kernel<<<(totalWu + 255) / 256, 256, 0, stream>>>(Wu, WuP, 3, totalWu);
    pack_w_kernel<<<(totalWg + 255) / 256, 256, 0, stream>>>(Wg, WgP, 4, totalWg);
    clear_flags_kernel<<<(nflag4 + 255) / 256, 256, 0, stream>>>((unsigned*)flags, nflag4);
    scatter_flags_kernel<<<(M + 255) / 256, 256, 0, stream>>>(kidx, flags, M);
    fused_kernel<<<M / BM, 256, 0, stream>>>(prev, cfg, kidx, vidx, WuP, WgP, bu, bg, out);
    copy_rows_kernel<<<2048, 256, 0, stream>>>((const f32x4*)prev, (f32x4*)out, flags, N_AST);
}

// Round 4
// 392.368 us; speedup vs baseline: 1.4628x; 1.3325x over previous
//
#include <hip/hip_runtime.h>
#include <hip/hip_bf16.h>

typedef __attribute__((ext_vector_type(8))) short short8;
typedef __attribute__((ext_vector_type(4))) float f32x4;
typedef __attribute__((ext_vector_type(4))) unsigned short u16x4;

#define D 256

static __device__ __forceinline__ unsigned short f2bf(float f) {
    union { __hip_bfloat16 h; unsigned short u; } v;
    v.h = __float2bfloat16(f);
    return v.u;
}
static __device__ __forceinline__ float bf2f(unsigned short h) {
    union { unsigned u; float f; } v; v.u = ((unsigned)h) << 16;
    return v.f;
}

// Pack W [K x 256] row-major f32 -> bf16 fragment-ready layout:
// dst[(((ntile*NKK)+kk)*64 + lane)*8 + j] = bf16(W[kk*32 + (lane>>4)*8 + j][ntile*16 + (lane&15)])
__global__ void pack_w_kernel(const float* __restrict__ W, unsigned short* __restrict__ dst,
                              int log2nkk, int total) {
    int p = blockIdx.x * blockDim.x + threadIdx.x;
    if (p >= total) return;
    int j     = p & 7;
    int lane  = (p >> 3) & 63;
    int kk    = (p >> 9) & ((1 << log2nkk) - 1);
    int ntile = p >> (9 + log2nkk);
    int k = kk * 32 + ((lane >> 4) * 8) + j;
    int n = ntile * 16 + (lane & 15);
    dst[p] = f2bf(W[k * D + n]);
}

__global__ void clear_flags_kernel(unsigned* __restrict__ f, int n) {
    int i = blockIdx.x * blockDim.x + threadIdx.x;
    if (i < n) f[i] = 0u;
}

__global__ void scatter_flags_kernel(const int* __restrict__ kidx,
                                     unsigned char* __restrict__ flags, int m) {
    int i = blockIdx.x * blockDim.x + threadIdx.x;
    if (i < m) flags[kidx[i]] = 1;
}

// One wave per AST row; copy only rows NOT covered by the scatter.
__global__ void copy_rows_kernel(const f32x4* __restrict__ src, f32x4* __restrict__ dst,
                                 const unsigned char* __restrict__ flags, int nrows) {
    int w    = (blockIdx.x * blockDim.x + threadIdx.x) >> 6;
    int lane = threadIdx.x & 63;
    int nw   = (gridDim.x * blockDim.x) >> 6;
    for (int row = w; row < nrows; row += nw) {
        if (flags[row]) continue;
        size_t idx = (size_t)row * 64 + lane;
        f32x4 v = __builtin_nontemporal_load(src + idx);
        __builtin_nontemporal_store(v, dst + idx);
    }
}

// projall[r] = relu(cfg[r] @ Wu + bu) as bf16, row-major [N_CFG][256].
// 64 contiguous cfg rows per block, 4 waves.
__global__ __launch_bounds__(256, 5) void projall_kernel(
    const float* __restrict__ cfg, const unsigned short* __restrict__ WuP,
    const float* __restrict__ bu, unsigned short* __restrict__ projall, int ncfg)
{
    __shared__ unsigned short Aub[64 * D];
    char* aubB = (char*)Aub;
    const int t = threadIdx.x, lane = t & 63, wid = t >> 6;
    const int lr = lane & 15, lk = lane >> 4;
    const int base = blockIdx.x * 64;

    #pragma unroll
    for (int i = 0; i < 16; ++i) {
        int row = wid * 16 + i;
        int r = base + row;
        f32x4 u = (f32x4){0.f, 0.f, 0.f, 0.f};
        if (r < ncfg) u = *(const f32x4*)(cfg + (size_t)r * D + lane * 4);
        int boff = (lane * 8) ^ ((row & 7) << 4);
        u16x4 hu;
        hu.x = f2bf(u.x); hu.y = f2bf(u.y); hu.z = f2bf(u.z); hu.w = f2bf(u.w);
        *(u16x4*)(aubB + row * 512 + boff) = hu;
    }
    __syncthreads();

    f32x4 acc[4][4];
    #pragma unroll
    for (int fm = 0; fm < 4; ++fm)
        #pragma unroll
        for (int fn = 0; fn < 4; ++fn)
            acc[fm][fn] = (f32x4){0.f, 0.f, 0.f, 0.f};

    #pragma unroll
    for (int kk = 0; kk < 8; ++kk) {
        short8 a[4], b[4];
        #pragma unroll
        for (int fm = 0; fm < 4; ++fm) {
            int row = fm * 16 + lr;
            int boff = (kk * 64 + lk * 16) ^ ((row & 7) << 4);
            a[fm] = *(const short8*)(aubB + row * 512 + boff);
        }
        #pragma unroll
        for (int fn = 0; fn < 4; ++fn) {
            int ntile = wid * 4 + fn;
            b[fn] = *(const short8*)(WuP + ((size_t)(ntile * 8 + kk) * 64 + lane) * 8);
        }
        #pragma unroll
        for (int fm = 0; fm < 4; ++fm)
            #pragma unroll
            for (int fn = 0; fn < 4; ++fn)
                acc[fm][fn] = __builtin_amdgcn_mfma_f32_16x16x32_bf16(a[fm], b[fn], acc[fm][fn], 0, 0, 0);
    }

    float bu4[4];
    #pragma unroll
    for (int fn = 0; fn < 4; ++fn) bu4[fn] = bu[wid * 64 + fn * 16 + lr];

    #pragma unroll
    for (int fm = 0; fm < 4; ++fm) {
        #pragma unroll
        for (int i = 0; i < 4; ++i) {
            int r = base + fm * 16 + lk * 4 + i;
            if (r >= ncfg) continue;
            #pragma unroll
            for (int fn = 0; fn < 4; ++fn) {
                float p = acc[fm][fn][i] + bu4[fn];
                p = p > 0.f ? p : 0.f;
                projall[(size_t)r * D + wid * 64 + fn * 16 + lr] = f2bf(p);
            }
        }
    }
}

// GEMM2-only fused pass: gather state(prev) + proj(projall) -> gate -> mix -> scatter.
// BM=64 rows per block, 512 threads (8 waves), each wave 64 rows x 32 cols.
__global__ __launch_bounds__(512, 4) void fused2_kernel(
    const float* __restrict__ prev, const unsigned short* __restrict__ projall,
    const int* __restrict__ kidx, const int* __restrict__ vidx,
    const unsigned short* __restrict__ WgP, const float* __restrict__ bg,
    float* __restrict__ out)
{
    __shared__ unsigned short Ast[64 * D];  // state bf16, swizzled 512B rows
    __shared__ unsigned short Apj[64 * D];  // proj  bf16, swizzled 512B rows
    char* astB = (char*)Ast;
    char* apjB = (char*)Apj;

    const int t    = threadIdx.x;
    const int lane = t & 63;
    const int wid  = t >> 6;      // 0..7
    const int lr   = lane & 15;
    const int lk   = lane >> 4;
    const int base = blockIdx.x * 64;

    // ---- stage state: 8 rows per wave, full-row coalesced f32x4 loads ----
    #pragma unroll
    for (int i = 0; i < 8; ++i) {
        int row = wid * 8 + i;
        int kr = kidx[base + row];
        f32x4 s = __builtin_nontemporal_load((const f32x4*)(prev + (size_t)kr * D) + lane);
        int boff = (lane * 8) ^ ((row & 7) << 4);
        u16x4 hs;
        hs.x = f2bf(s.x); hs.y = f2bf(s.y); hs.z = f2bf(s.z); hs.w = f2bf(s.w);
        *(u16x4*)(astB + row * 512 + boff) = hs;
    }
    // ---- stage proj: bf16 rows (512B), 2 rows per instruction ----
    #pragma unroll
    for (int i = 0; i < 4; ++i) {
        int row = wid * 8 + i * 2 + (lane >> 5);
        int vr = vidx[base + row];
        short8 pv = *(const short8*)(projall + (size_t)vr * D + (lane & 31) * 8);
        int boff = ((lane & 31) * 16) ^ ((row & 7) << 4);
        *(short8*)(apjB + row * 512 + boff) = pv;
    }
    __syncthreads();

    // ---- GEMM2: logits = [state, proj] @ Wg, K = 512 ----
    f32x4 acc2[4][2];
    #pragma unroll
    for (int fm = 0; fm < 4; ++fm)
        #pragma unroll
        for (int fn = 0; fn < 2; ++fn)
            acc2[fm][fn] = (f32x4){0.f, 0.f, 0.f, 0.f};

    #pragma unroll
    for (int kk = 0; kk < 16; ++kk) {
        const char* Asrc = (kk < 8) ? astB : apjB;
        int kkl = kk & 7;
        short8 a[4], b[2];
        #pragma unroll
        for (int fm = 0; fm < 4; ++fm) {
            int row = fm * 16 + lr;
            int boff = (kkl * 64 + lk * 16) ^ ((row & 7) << 4);
            a[fm] = *(const short8*)(Asrc + row * 512 + boff);
        }
        #pragma unroll
        for (int fn = 0; fn < 2; ++fn) {
            int ntile = wid * 2 + fn;
            b[fn] = *(const short8*)(WgP + ((size_t)(ntile * 16 + kk) * 64 + lane) * 8);
        }
        #pragma unroll
        for (int fm = 0; fm < 4; ++fm)
            #pragma unroll
            for (int fn = 0; fn < 2; ++fn)
                acc2[fm][fn] = __builtin_amdgcn_mfma_f32_16x16x32_bf16(a[fm], b[fn], acc2[fm][fn], 0, 0, 0);
    }

    // ---- epilogue: gate = sigmoid(logits + bg); out = g*state + (1-g)*proj ----
    float bg2[2];
    #pragma unroll
    for (int fn = 0; fn < 2; ++fn) bg2[fn] = bg[wid * 32 + fn * 16 + lr];

    #pragma unroll
    for (int fm = 0; fm < 4; ++fm) {
        #pragma unroll
        for (int i = 0; i < 4; ++i) {
            int row = fm * 16 + lk * 4 + i;
            int kr = kidx[base + row];
            float* orow = out + (size_t)kr * D;
            #pragma unroll
            for (int fn = 0; fn < 2; ++fn) {
                int col = wid * 32 + fn * 16 + lr;
                float x = acc2[fm][fn][i] + bg2[fn];
                float g = 1.f / (1.f + __expf(-x));
                int boff = (col * 2) ^ ((row & 7) << 4);
                float st = bf2f(*(const unsigned short*)(astB + row * 512 + boff));
                float pj = bf2f(*(const unsigned short*)(apjB + row * 512 + boff));
                __builtin_nontemporal_store(g * st + (1.f - g) * pj, orow + col);
            }
        }
    }
}

// ---------------- fallback (proven R3 path) for small ws ----------------
__global__ __launch_bounds__(256, 5) void fused_kernel(
    const float* __restrict__ prev, const float* __restrict__ cfg,
    const int* __restrict__ kidx, const int* __restrict__ vidx,
    const unsigned short* __restrict__ WuP, const unsigned short* __restrict__ WgP,
    const float* __restrict__ bu, const float* __restrict__ bg,
    float* __restrict__ out)
{
    __shared__ unsigned short Ast[32 * D];
    __shared__ unsigned short Aub[32 * D];
    char* astB = (char*)Ast;
    char* aubB = (char*)Aub;
    const int t = threadIdx.x, lane = t & 63, wid = t >> 6;
    const int lr = lane & 15, lk = lane >> 4;
    const int base = blockIdx.x * 32;

    #pragma unroll
    for (int i = 0; i < 8; ++i) {
        int row = wid * 8 + i;
        int kr = kidx[base + row];
        int vr = vidx[base + row];
        f32x4 s = *(const f32x4*)(prev + (size_t)kr * D + lane * 4);
        f32x4 u = *(const f32x4*)(cfg  + (size_t)vr * D + lane * 4);
        int boff = (lane * 8) ^ ((row & 7) << 4);
        u16x4 hs, hu;
        hs.x = f2bf(s.x); hs.y = f2bf(s.y); hs.z = f2bf(s.z); hs.w = f2bf(s.w);
        hu.x = f2bf(u.x); hu.y = f2bf(u.y); hu.z = f2bf(u.z); hu.w = f2bf(u.w);
        *(u16x4*)(astB + row * 512 + boff) = hs;
        *(u16x4*)(aubB + row * 512 + boff) = hu;
    }
    __syncthreads();

    f32x4 acc[2][4];
    #pragma unroll
    for (int fm = 0; fm < 2; ++fm)
        #pragma unroll
        for (int fn = 0; fn < 4; ++fn) acc[fm][fn] = (f32x4){0.f,0.f,0.f,0.f};

    #pragma unroll
    for (int kk = 0; kk < 8; ++kk) {
        short8 a[2], b[4];
        #pragma unroll
        for (int fm = 0; fm < 2; ++fm) {
            int row = fm * 16 + lr;
            int boff = (kk * 64 + lk * 16) ^ ((row & 7) << 4);
            a[fm] = *(const short8*)(aubB + row * 512 + boff);
        }
        #pragma unroll
        for (int fn = 0; fn < 4; ++fn)
            b[fn] = *(const short8*)(WuP + ((size_t)((wid*4+fn) * 8 + kk) * 64 + lane) * 8);
        #pragma unroll
        for (int fm = 0; fm < 2; ++fm)
            #pragma unroll
            for (int fn = 0; fn < 4; ++fn)
                acc[fm][fn] = __builtin_amdgcn_mfma_f32_16x16x32_bf16(a[fm], b[fn], acc[fm][fn], 0, 0, 0);
    }

    float bu4[4];
    #pragma unroll
    for (int fn = 0; fn < 4; ++fn) bu4[fn] = bu[wid * 64 + fn * 16 + lr];
    __syncthreads();

    #pragma unroll
    for (int fm = 0; fm < 2; ++fm)
        #pragma unroll
        for (int fn = 0; fn < 4; ++fn)
            #pragma unroll
            for (int i = 0; i < 4; ++i) {
                float p = acc[fm][fn][i] + bu4[fn];
                p = p > 0.f ? p : 0.f;
                int row = fm * 16 + lk * 4 + i;
                int col = wid * 64 + fn * 16 + lr;
                *(unsigned short*)(aubB + row * 512 + ((col*2) ^ ((row&7)<<4))) = f2bf(p);
            }
    __syncthreads();

    f32x4 acc2[2][4];
    #pragma unroll
    for (int fm = 0; fm < 2; ++fm)
        #pragma unroll
        for (int fn = 0; fn < 4; ++fn) acc2[fm][fn] = (f32x4){0.f,0.f,0.f,0.f};

    #pragma unroll
    for (int kk = 0; kk < 16; ++kk) {
        const char* Asrc = (kk < 8) ? astB : aubB;
        int kkl = kk & 7;
        short8 a[2], b[4];
        #pragma unroll
        for (int fm = 0; fm < 2; ++fm) {
            int row = fm * 16 + lr;
            int boff = (kkl * 64 + lk * 16) ^ ((row & 7) << 4);
            a[fm] = *(const short8*)(Asrc + row * 512 + boff);
        }
        #pragma unroll
        for (int fn = 0; fn < 4; ++fn)
            b[fn] = *(const short8*)(WgP + ((size_t)((wid*4+fn) * 16 + kk) * 64 + lane) * 8);
        #pragma unroll
        for (int fm = 0; fm < 2; ++fm)
            #pragma unroll
            for (int fn = 0; fn < 4; ++fn)
                acc2[fm][fn] = __builtin_amdgcn_mfma_f32_16x16x32_bf16(a[fm], b[fn], acc2[fm][fn], 0, 0, 0);
    }

    float bg4[4];
    #pragma unroll
    for (int fn = 0; fn < 4; ++fn) bg4[fn] = bg[wid * 64 + fn * 16 + lr];

    #pragma unroll
    for (int fm = 0; fm < 2; ++fm)
        #pragma unroll
        for (int i = 0; i < 4; ++i) {
            int row = fm * 16 + lk * 4 + i;
            int kr = kidx[base + row];
            float* orow = out + (size_t)kr * D;
            #pragma unroll
            for (int fn = 0; fn < 4; ++fn) {
                int col = wid * 64 + fn * 16 + lr;
                float x = acc2[fm][fn][i] + bg4[fn];
                float g = 1.f / (1.f + __expf(-x));
                int boff = (col * 2) ^ ((row & 7) << 4);
                float st = bf2f(*(const unsigned short*)(astB + row * 512 + boff));
                float pj = bf2f(*(const unsigned short*)(aubB + row * 512 + boff));
                orow[col] = g * st + (1.f - g) * pj;
            }
        }
}

extern "C" void kernel_launch(void* const* d_in, const int* in_sizes, int n_in,
                              void* d_out, int out_size, void* d_ws, size_t ws_size,
                              hipStream_t stream) {
    const float* prev = (const float*)d_in[0];
    const float* cfg  = (const float*)d_in[1];
    const int* kidx   = (const int*)d_in[2];
    const int* vidx   = (const int*)d_in[3];
    const float* Wu   = (const float*)d_in[4];
    const float* bu   = (const float*)d_in[5];
    const float* Wg   = (const float*)d_in[6];
    const float* bg   = (const float*)d_in[7];
    float* out = (float*)d_out;

    const int N_AST = in_sizes[0] / D;  // 500000
    const int N_CFG = in_sizes[1] / D;  // 100000
    const int M     = in_sizes[2];      // 400000

    unsigned short* WuP = (unsigned short*)d_ws;               // 128 KB
    unsigned short* WgP = WuP + 256 * 256;                     // 256 KB
    unsigned char* flags = (unsigned char*)(WgP + 512 * 256);  // N_AST bytes
    unsigned short* projall = (unsigned short*)((char*)d_ws + (1 << 20));  // N_CFG*256 bf16

    const int totalWu = 256 * 256;
    const int totalWg = 512 * 256;
    const int nflag4  = (N_AST + 3) / 4;
    const size_t needed = (size_t)(1 << 20) + (size_t)N_CFG * D * 2;

    pack_w_kernel<<<(totalWu + 255) / 256, 256, 0, stream>>>(Wu, WuP, 3, totalWu);
    pack_w_kernel<<<(totalWg + 255) / 256, 256, 0, stream>>>(Wg, WgP, 4, totalWg);
    clear_flags_kernel<<<(nflag4 + 255) / 256, 256, 0, stream>>>((unsigned*)flags, nflag4);
    scatter_flags_kernel<<<(M + 255) / 256, 256, 0, stream>>>(kidx, flags, M);

    if (ws_size >= needed) {
        projall_kernel<<<(N_CFG + 63) / 64, 256, 0, stream>>>(cfg, WuP, bu, projall, N_CFG);
        fused2_kernel<<<M / 64, 512, 0, stream>>>(prev, projall, kidx, vidx, WgP, bg, out);
    } else {
        fused_kernel<<<M / 32, 256, 0, stream>>>(prev, cfg, kidx, vidx, WuP, WgP, bu, bg, out);
    }
    copy_rows_kernel<<<2048, 256, 0, stream>>>((const f32x4*)prev, (f32x4*)out, flags, N_AST);
}